// Round 4
// baseline (67.728 us; speedup 1.0000x reference)
//
#include <hip/hip_runtime.h>

// Permute: out = X @ Q where Q is a one-hot permutation matrix.
// (X@Q)[b][j] = X[b][inv[j]] with inv = perm^{-1}, recovered by scanning Q.

#define FEATURES 4096
#define BATCH 8192
#define RPB 4                       // rows per block (double-buffered pipeline)
#define NBLK (BATCH / RPB)          // 2048 blocks
#define Q4R (FEATURES / 4)          // 1024 float4 per row
#define QPT (Q4R / 256)             // 4 float4 per thread per row

typedef const __attribute__((address_space(1))) void* gptr_t;
typedef __attribute__((address_space(3))) void* lptr_t;

// Kernel 1: scan Q (FEATURES x FEATURES, row-major) for nonzeros.
// Q[i][j] != 0  =>  perm[i] == j  =>  inv[j] = i.
// Exactly one nonzero per column => every inv[j] written exactly once per call.
__global__ __launch_bounds__(256) void build_inv_kernel(
    const float4* __restrict__ Q4, int* __restrict__ inv, int total4) {
    int idx = blockIdx.x * blockDim.x + threadIdx.x;
    int stride = gridDim.x * blockDim.x;
    for (int i = idx; i < total4; i += stride) {
        float4 v = Q4[i];
        if (v.x == 0.f && v.y == 0.f && v.z == 0.f && v.w == 0.f) continue;
        int base = i << 2;                 // flat element index
        int row  = base >> 12;             // / FEATURES (4096)
        int col  = base & (FEATURES - 1);  // % FEATURES
        if (v.x != 0.f) inv[col + 0] = row;
        if (v.y != 0.f) inv[col + 1] = row;
        if (v.z != 0.f) inv[col + 2] = row;
        if (v.w != 0.f) inv[col + 3] = row;
    }
}

// Kernel 2: each block owns RPB rows with a double-buffered LDS pipeline
// (m201-style counted vmcnt + raw barriers):
//   issue global_load_lds for row r+1 into buf[(r+1)&1]
//   s_waitcnt vmcnt(4)   -- row r's 4 loads done (in-order count); prefetch flies on
//   s_barrier            -- all waves' row-r staging visible
//   gather row r from LDS -> coalesced float4 stores
//   s_barrier            -- all readers done before buf[r&1] is restaged next iter
// vmcnt ledger (per wave, in issue order): [row r loads(4)][stores(4)][row r+1 loads(4)]
// => vmcnt(4) retires the oldest 8 (row r + stores), leaves the prefetch in flight.
__global__ __launch_bounds__(256) void permute_pipe_kernel(
    const float4* __restrict__ X4, const int4* __restrict__ inv4,
    float4* __restrict__ out4) {
    __shared__ float buf[2][FEATURES];     // 32 KB -> 5 blocks/CU, 20 waves
    const int t = threadIdx.x;
    const size_t r0 = (size_t)blockIdx.x * RPB;

    // Gather indices: loaded once per block (L2-resident 16 KB table).
    int4 idx[QPT];
#pragma unroll
    for (int q = 0; q < QPT; ++q) idx[q] = inv4[t + q * 256];

    // Prologue: stage row r0 into buf[0].
    {
        const float4* __restrict__ x = X4 + r0 * Q4R;
        float4* l = (float4*)buf[0];
#pragma unroll
        for (int q = 0; q < QPT; ++q)
            __builtin_amdgcn_global_load_lds((gptr_t)(x + t + q * 256),
                                             (lptr_t)(l + t + q * 256), 16, 0, 0);
    }

#pragma unroll
    for (int r = 0; r < RPB; ++r) {
        // Issue next-row staging; it stays in flight across the barrier.
        if (r + 1 < RPB) {
            const float4* __restrict__ x = X4 + (r0 + r + 1) * Q4R;
            float4* l = (float4*)buf[(r + 1) & 1];
#pragma unroll
            for (int q = 0; q < QPT; ++q)
                __builtin_amdgcn_global_load_lds((gptr_t)(x + t + q * 256),
                                                 (lptr_t)(l + t + q * 256), 16, 0, 0);
        }

        asm volatile("s_waitcnt vmcnt(4)" ::: "memory");
        __builtin_amdgcn_s_barrier();

        const float* __restrict__ row = buf[r & 1];
        float4* __restrict__ o = out4 + (r0 + r) * Q4R;
#pragma unroll
        for (int q = 0; q < QPT; ++q) {
            int4 id = idx[q];
            float4 v;
            v.x = row[id.x];
            v.y = row[id.y];
            v.z = row[id.z];
            v.w = row[id.w];
            o[t + q * 256] = v;   // coalesced 16 B/lane store
        }

        // Readers of buf[r&1] must finish before it is restaged next iter.
        if (r + 1 < RPB) __builtin_amdgcn_s_barrier();
    }
}

extern "C" void kernel_launch(void* const* d_in, const int* in_sizes, int n_in,
                              void* d_out, int out_size, void* d_ws, size_t ws_size,
                              hipStream_t stream) {
    const float* X = (const float*)d_in[0];
    const float* Q = (const float*)d_in[1];
    float* out = (float*)d_out;
    int* inv = (int*)d_ws;  // 4096 ints = 16 KB scratch

    const int total4 = (FEATURES * FEATURES) / 4;  // 4M float4 quads
    build_inv_kernel<<<2048, 256, 0, stream>>>((const float4*)Q, inv, total4);
    permute_pipe_kernel<<<NBLK, 256, 0, stream>>>(
        (const float4*)X, (const int4*)inv, (float4*)out);
}